// Round 4
// baseline (162.363 us; speedup 1.0000x reference)
//
#include <hip/hip_runtime.h>
#include <hip/hip_bf16.h>

// PureCascadedBitFFN: distance (512,4096) f32 -> bits (512,4096,16) f32.
// Reference cascade == bits of N = ceil(d - 0.5), LSB-first (proof R0:
// sigmoid>0.5 <=> arg>0; cascade subtractions Sterbenz-exact; d-0.5f exact
// on [0,65536)). absmax 0.0 verified R0-R2.
//
// R3 = MEASUREMENT ROUND: kernel launched TWICE (idempotent, deterministic,
// graph-capture safe). Kernel never appears in rocprof top-5 (all entries
// are the harness's 512 MiB 0xAA poison fill @ ~82 us), so graded dur_us
// includes harness dispatches. delta(dur_us) vs R2 = one kernel duration:
//   ~25 us -> kernel at write roofline (136 MiB @ ~6 TB/s), revert & stop.
//   ~58 us -> kernel genuinely slow, investigate store pipe.
// Kernel body identical to R2 (persistent grid-stride, 2048x256, unroll x4,
// lane-contiguous float4 stores).

#define NUM_BITS 16
#define UNROLL 4

__device__ __forceinline__ float4 nibble_of(const float* __restrict__ din, int t) {
    int e = t >> 2;        // input element
    int q = (t & 3) << 2;  // starting bit of this thread's nibble
    float d = din[e];
    unsigned N = (unsigned)(int)ceilf(d - 0.5f);  // == reference cascade value
    return make_float4((float)((N >> (q + 0)) & 1u),
                       (float)((N >> (q + 1)) & 1u),
                       (float)((N >> (q + 2)) & 1u),
                       (float)((N >> (q + 3)) & 1u));
}

__global__ __launch_bounds__(256) void cascaded_bits_kernel(
    const float* __restrict__ din, float4* __restrict__ dout, int n4) {
    const int stride = gridDim.x * blockDim.x;          // 524,288 threads
    int t0 = blockIdx.x * blockDim.x + threadIdx.x;

    int t = t0;
    for (; t + (UNROLL - 1) * stride < n4; t += UNROLL * stride) {
#pragma unroll
        for (int u = 0; u < UNROLL; ++u) {
            dout[t + u * stride] = nibble_of(din, t + u * stride);
        }
    }
    for (; t < n4; t += stride) {
        dout[t] = nibble_of(din, t);
    }
}

extern "C" void kernel_launch(void* const* d_in, const int* in_sizes, int n_in,
                              void* d_out, int out_size, void* d_ws, size_t ws_size,
                              hipStream_t stream) {
    const float* distance = (const float*)d_in[0];
    float4* out = (float4*)d_out;
    int n = in_sizes[0];      // 512*4096 = 2,097,152 elements
    int n4 = n * 4;           // 8,388,608 output float4s

    const int block = 256;
    const int grid = 2048;    // 8 blocks/CU on 256 CUs
    // Launched twice on purpose this round: delta vs R2 total time measures
    // one kernel duration exactly (kernel is idempotent).
    cascaded_bits_kernel<<<grid, block, 0, stream>>>(distance, out, n4);
    cascaded_bits_kernel<<<grid, block, 0, stream>>>(distance, out, n4);
}

// Round 5
// 139.709 us; speedup vs baseline: 1.1622x; 1.1622x over previous
//
#include <hip/hip_runtime.h>
#include <hip/hip_bf16.h>

// PureCascadedBitFFN: distance (512,4096) f32 -> bits (512,4096,16) f32.
// Reference cascade == bits of N = ceil(d - 0.5), LSB-first (proof R0:
// sigmoid>0.5 <=> arg>0; all cascade subtractions Sterbenz-exact; d-0.5f
// exact on [0,65536)). absmax 0.0 verified R0-R4.
//
// FINAL (R2 body, single launch). Persistent grid-stride kernel, 2048x256
// (8 blocks/CU), one thread per output float4 (lane-contiguous 16 B/lane
// stores = 1 KiB per wave store instruction), unroll x4 for 4 independent
// load->store chains per wave.
//
// Measured via R3 double-launch differencing: kernel = 22.1 us for
// 8 MiB read + 128 MiB write = 6.16 TB/s, ~98% of the 6.3 TB/s achievable
// HBM ceiling (harness's own 512 MiB fill: 6.37 TB/s). Write-bandwidth
// roofline reached. Graded dur_us (~140 us) is dominated by ~118 us of
// fixed harness re-poison/restore dispatches outside our control.

#define NUM_BITS 16
#define UNROLL 4

__device__ __forceinline__ float4 nibble_of(const float* __restrict__ din, int t) {
    int e = t >> 2;        // input element
    int q = (t & 3) << 2;  // starting bit of this thread's nibble
    float d = din[e];
    unsigned N = (unsigned)(int)ceilf(d - 0.5f);  // == reference cascade value
    return make_float4((float)((N >> (q + 0)) & 1u),
                       (float)((N >> (q + 1)) & 1u),
                       (float)((N >> (q + 2)) & 1u),
                       (float)((N >> (q + 3)) & 1u));
}

__global__ __launch_bounds__(256) void cascaded_bits_kernel(
    const float* __restrict__ din, float4* __restrict__ dout, int n4) {
    const int stride = gridDim.x * blockDim.x;          // 524,288 threads
    int t0 = blockIdx.x * blockDim.x + threadIdx.x;

    int t = t0;
    for (; t + (UNROLL - 1) * stride < n4; t += UNROLL * stride) {
#pragma unroll
        for (int u = 0; u < UNROLL; ++u) {
            dout[t + u * stride] = nibble_of(din, t + u * stride);
        }
    }
    for (; t < n4; t += stride) {  // tail: empty for this shape, kept for safety
        dout[t] = nibble_of(din, t);
    }
}

extern "C" void kernel_launch(void* const* d_in, const int* in_sizes, int n_in,
                              void* d_out, int out_size, void* d_ws, size_t ws_size,
                              hipStream_t stream) {
    const float* distance = (const float*)d_in[0];
    float4* out = (float4*)d_out;
    int n = in_sizes[0];      // 512*4096 = 2,097,152 elements
    int n4 = n * 4;           // 8,388,608 output float4s

    const int block = 256;
    const int grid = 2048;    // 8 blocks/CU on 256 CUs
    cascaded_bits_kernel<<<grid, block, 0, stream>>>(distance, out, n4);
}